// Round 14
// baseline (142.732 us; speedup 1.0000x reference)
//
#include <hip/hip_runtime.h>

typedef __attribute__((ext_vector_type(8))) short bf16x8;
typedef __attribute__((ext_vector_type(4))) float f32x4;

#define AS3 __attribute__((address_space(3)))
#define AS1 __attribute__((address_space(1)))

__device__ __forceinline__ unsigned short f2bf(float f) {
  unsigned u = __float_as_uint(f);
  u += 0x7fffu + ((u >> 16) & 1u);
  return (unsigned short)(u >> 16);
}
__device__ __forceinline__ float bf2f(unsigned short v) {
  return __uint_as_float((unsigned)v << 16);
}

// ---------------- kernel 1: transpose + pad + bf16 + border-zero + pool partials
__global__ void transpose_kernel(const float* __restrict__ x,
                                 unsigned short* __restrict__ xTp,
                                 float* __restrict__ part) {
  __shared__ unsigned short tb[64][258];
  __shared__ float redf[4][256];
  const int blk = blockIdx.x;
  const int b = blk >> 6, y = blk & 63;
  const int t = threadIdx.x;
  const int l = t & 63, w = t >> 6;
  const int coff = l >> 4;
  const int x4 = (l & 15) << 2;
  const float* src = x + (size_t)b * 256 * 4096 + (size_t)y * 64;
#pragma unroll 4
  for (int i = 0; i < 16; ++i) {
    const int c = w * 64 + i * 4 + coff;
    const float4 v = *reinterpret_cast<const float4*>(&src[(size_t)c * 4096 + x4]);
    tb[x4 + 0][c] = f2bf(v.x);
    tb[x4 + 1][c] = f2bf(v.y);
    tb[x4 + 2][c] = f2bf(v.z);
    tb[x4 + 3][c] = f2bf(v.w);
  }
  __syncthreads();
  unsigned short* dstb = xTp + (size_t)b * (4356 * 256);
  unsigned short* dst = dstb + ((size_t)(y + 1) * 66 + 1) * 256;
  float s0 = 0.f, s1 = 0.f, s2 = 0.f, s3 = 0.f;
#pragma unroll 4
  for (int i = 0; i < 16; ++i) {
    const int xx = w * 16 + i;
    ushort2 v0 = *(const ushort2*)&tb[xx][l * 4];
    ushort2 v1 = *(const ushort2*)&tb[xx][l * 4 + 2];
    s0 += bf2f(v0.x); s1 += bf2f(v0.y); s2 += bf2f(v1.x); s3 += bf2f(v1.y);
    ushort4 v = {v0.x, v0.y, v1.x, v1.y};
    *(ushort4*)&dst[(size_t)xx * 256 + l * 4] = v;
  }
  redf[w][l * 4 + 0] = s0;
  redf[w][l * 4 + 1] = s1;
  redf[w][l * 4 + 2] = s2;
  redf[w][l * 4 + 3] = s3;
  unsigned short* rowpad = dstb + ((size_t)(y + 1) * 66) * 256;
  rowpad[t] = 0;
  rowpad[65 * 256 + t] = 0;
  if (y == 0)
    for (int xx = 0; xx < 66; ++xx) dstb[(size_t)xx * 256 + t] = 0;
  if (y == 63)
    for (int xx = 0; xx < 66; ++xx) dstb[(size_t)(65 * 66 + xx) * 256 + t] = 0;
  __syncthreads();
  part[((size_t)(b * 64 + y)) * 256 + t] =
      redf[0][t] + redf[1][t] + redf[2][t] + redf[3][t];
}

// ---------------- kernel 2: fused pool-finish + attention MLP + softmax ----
// part[16*64][256] -> (LDS pooled) -> att[16][4]; pooled never hits global.
__global__ void poolattn_kernel(const float* __restrict__ part,
                                const float* __restrict__ w1,
                                const float* __restrict__ bng,
                                const float* __restrict__ bnb,
                                const float* __restrict__ bnm,
                                const float* __restrict__ bnv,
                                const float* __restrict__ w2,
                                float* __restrict__ att) {
  __shared__ float pooledS[16][256];
  __shared__ float hbuf[256];
  const int t = threadIdx.x;
  // phase 1: finish pool. thread t sums column c=t for all 16 samples.
  for (int bb = 0; bb < 16; ++bb) {
    float s = 0.f;
    for (int y = 0; y < 64; ++y) s += part[((size_t)(bb * 64 + y)) * 256 + t];
    pooledS[bb][t] = s * (1.0f / 4096.0f);
  }
  __syncthreads();
  // phase 2: attn MLP (identical math to previous attn_kernel)
  const int b = t >> 4, i = t & 15;
  float s = 0.f;
  for (int c = 0; c < 256; ++c) s += pooledS[b][c] * w1[i * 256 + c];
  float h = (s - bnm[i]) * rsqrtf(bnv[i] + 1e-5f) * bng[i] + bnb[i];
  hbuf[t] = fmaxf(h, 0.f);
  __syncthreads();
  if (t < 64) {
    const int bb = t >> 2, k = t & 3;
    float l = 0.f;
    for (int j = 0; j < 16; ++j) l += hbuf[bb * 16 + j] * w2[k * 16 + j];
    float m = l;
    m = fmaxf(m, __shfl_xor(m, 1, 64));
    m = fmaxf(m, __shfl_xor(m, 2, 64));
    float e = expf(l - m);
    float sum = e;
    sum += __shfl_xor(sum, 1, 64);
    sum += __shfl_xor(sum, 2, 64);
    att[bb * 4 + k] = e / sum;
  }
}

// ---------------- kernel 3: aggregate per-sample kernels ----------------
__global__ void agg_kernel(const float* __restrict__ att,
                           const float* __restrict__ wgt,
                           unsigned short* __restrict__ agg) {
  const int o = blockIdx.x;
  const int bh = blockIdx.y;
  const int c = threadIdx.x;
  float w[4][9];
#pragma unroll
  for (int k = 0; k < 4; ++k) {
    const float* wp = wgt + ((size_t)((k << 8) + o) * 256 + c) * 9;
#pragma unroll
    for (int t = 0; t < 9; ++t) w[k][t] = wp[t];
  }
  __shared__ float attS[64];
  if (c < 64) attS[c] = att[c];
  __syncthreads();
#pragma unroll 1
  for (int b = bh * 8; b < bh * 8 + 8; ++b) {
    const float a0 = attS[b * 4 + 0], a1 = attS[b * 4 + 1];
    const float a2 = attS[b * 4 + 2], a3 = attS[b * 4 + 3];
#pragma unroll
    for (int t = 0; t < 9; ++t) {
      const float v = a0 * w[0][t] + a1 * w[1][t] + a2 * w[2][t] + a3 * w[3][t];
      agg[(((size_t)(b * 9 + t) * 256) + o) * 256 + c] = f2bf(v);
    }
  }
}

// ---------------- kernel 4: per-sample implicit-GEMM conv (bf16 MFMA) ----
// FROZEN at session-best structure (R13, 69.5us): tile 256x128, 4 waves
// (2Mx2N) of 128x64, A-halo staged per c0 (reused 9 taps), B ring-4
// stage-ahead-2, 1 barrier/tap, end-of-tap frag prefetch.
__global__ __launch_bounds__(256, 2) void conv_kernel(
    const unsigned short* __restrict__ xTp,
    const unsigned short* __restrict__ agg,
    float* __restrict__ out) {
  __shared__ unsigned short lds[448 * 32 + 4 * 128 * 32];  // 61440 B
  AS3 char* ldsA3 = (AS3 char*)lds;
  AS3 char* ldsB3 = ((AS3 char*)lds) + 28672;

  const int bid = blockIdx.x;
  const int b = bid & 15;   // XCD = b%8
  const int rest = bid >> 4;
  const int mt = rest >> 1;
  const int nh = rest & 1;
  const int p0 = mt << 8;
  const int rowA0 = mt * 264;

  const int tid = threadIdx.x;
  const int lane = tid & 63;
  const int wave = tid >> 6;
  const int wm = wave >> 1;
  const int wn = wave & 1;

  const int srow = tid >> 2;
  const int scol = ((tid & 3) ^ ((tid >> 3) & 3)) << 3;
  const int sdst = srow * 64 + (tid & 3) * 16;

  const unsigned short* xbs =
      xTp + (size_t)b * (4356 * 256) + (size_t)rowA0 * 256 + scol;
  const unsigned short* aggs =
      agg + ((size_t)(b * 9) * 256 + nh * 128 + srow) * 256 + scol;

  auto stageA = [&](int c0) {
#pragma unroll
    for (int i = 0; i < 7; ++i) {
      const int h = srow + (i << 6);
      const int hs = h > 395 ? 395 : h;
      __builtin_amdgcn_global_load_lds(
          (const AS1 void*)(xbs + (size_t)hs * 256 + c0 * 32),
          (AS3 void*)(ldsA3 + sdst + (i << 12)), 16, 0, 0);
    }
  };
  auto stageB = [&](int c02, int tap2, int slot) {
#pragma unroll
    for (int j = 0; j < 2; ++j) {
      __builtin_amdgcn_global_load_lds(
          (const AS1 void*)(aggs + tap2 * 65536 + (j << 14) + c02 * 32),
          (AS3 void*)(ldsB3 + slot * 8192 + sdst + (j << 12)), 16, 0, 0);
    }
  };

  const int l15 = lane & 15;
  const int lhi = lane >> 4;
  const int hb0 = wm * 132 + l15;
  const int rslotB = (lhi ^ ((l15 >> 1) & 3)) << 4;
  int boffs[4];
#pragma unroll
  for (int n = 0; n < 4; ++n)
    boffs[n] = 28672 + (wn * 64 + n * 16 + l15) * 64 + rslotB;

  f32x4 acc[8][4];
#pragma unroll
  for (int m = 0; m < 8; ++m)
#pragma unroll
    for (int n = 0; n < 4; ++n) acc[m][n] = (f32x4){0.f, 0.f, 0.f, 0.f};

#define LDFRAGS(tt)                                                        \
  {                                                                        \
    const int dy_ = (tt) / 3, dx_ = (tt) % 3;                              \
    const int slotR_ = (c0 + (tt)) & 3;                                    \
    _Pragma("unroll") for (int m = 0; m < 8; ++m) {                        \
      const int h_ = hb0 + ((m >> 2) + dy_) * 66 + (m & 3) * 16 + dx_;     \
      af[m] = *(const bf16x8*)((const char*)lds + h_ * 64 +                \
                               ((lhi ^ ((h_ >> 1) & 3)) << 4));            \
    }                                                                      \
    _Pragma("unroll") for (int n = 0; n < 4; ++n)                          \
      bfr[n] = *(const bf16x8*)((const char*)lds + slotR_ * 8192 + boffs[n]); \
  }

  stageB(0, 0, 0);
  stageB(0, 1, 1);

#pragma unroll 1
  for (int c0 = 0; c0 < 8; ++c0) {
    __builtin_amdgcn_s_barrier();  // all waves consumed A(c0-1)
    stageA(c0);
    asm volatile("s_waitcnt vmcnt(0)" ::: "memory");
    __builtin_amdgcn_s_barrier();
    __builtin_amdgcn_sched_barrier(0);
    bf16x8 af[8], bfr[4];
    LDFRAGS(0);  // preload tap0 frags (B slot c0&3 drained above)
#pragma unroll
    for (int tap = 0; tap < 9; ++tap) {
      if (tap != 0) {
        asm volatile("s_waitcnt vmcnt(0)" ::: "memory");
        __builtin_amdgcn_s_barrier();
        __builtin_amdgcn_sched_barrier(0);
      }
      {  // stage B(tap+2)
        int c02, tap2;
        if (tap <= 6) { c02 = c0; tap2 = tap + 2; }
        else { c02 = c0 + 1; tap2 = tap - 7; }
        if (c02 > 7) { c02 = 7; tap2 = 8; }  // tail dup, uniform counts
        stageB(c02, tap2, (c0 + tap + 2) & 3);
      }
      __builtin_amdgcn_s_setprio(1);
#pragma unroll
      for (int m = 0; m < 8; ++m)
#pragma unroll
        for (int n = 0; n < 4; ++n)
          acc[m][n] = __builtin_amdgcn_mfma_f32_16x16x32_bf16(af[m], bfr[n],
                                                              acc[m][n], 0, 0, 0);
      __builtin_amdgcn_s_setprio(0);
      if (tap < 8) LDFRAGS(tap + 1);
    }
  }

  // epilogue: D row=(lane>>4)*4+reg is p, col=lane&15 is cout
#pragma unroll
  for (int m = 0; m < 8; ++m) {
    const int p = p0 + wm * 128 + (m >> 2) * 64 + (m & 3) * 16 + (lhi << 2);
#pragma unroll
    for (int n = 0; n < 4; ++n) {
      const int co = nh * 128 + wn * 64 + n * 16 + l15;
      float* dst = out + ((size_t)(b * 256 + co) << 12) + p;
      *reinterpret_cast<f32x4*>(dst) = acc[m][n];
    }
  }
#undef LDFRAGS
}

extern "C" void kernel_launch(void* const* d_in, const int* in_sizes, int n_in,
                              void* d_out, int out_size, void* d_ws, size_t ws_size,
                              hipStream_t stream) {
  const float* x = (const float*)d_in[0];
  const float* w1 = (const float*)d_in[1];
  const float* bng = (const float*)d_in[2];
  const float* bnb = (const float*)d_in[3];
  const float* bnm = (const float*)d_in[4];
  const float* bnv = (const float*)d_in[5];
  const float* w2 = (const float*)d_in[6];
  const float* wgt = (const float*)d_in[7];
  float* out = (float*)d_out;

  char* ws = (char*)d_ws;
  const size_t xtp_bytes = (size_t)16 * 4356 * 256 * 2;    // 35,684,352
  const size_t agg_bytes = (size_t)16 * 9 * 256 * 256 * 2; // 18,874,368
  unsigned short* xTp = (unsigned short*)ws;
  unsigned short* agg = (unsigned short*)(ws + xtp_bytes);
  float* att = (float*)(ws + xtp_bytes + agg_bytes + 16384);
  float* part = (float*)(ws + xtp_bytes + agg_bytes + 20480);

  transpose_kernel<<<1024, 256, 0, stream>>>(x, xTp, part);
  poolattn_kernel<<<1, 256, 0, stream>>>(part, w1, bng, bnb, bnm, bnv, w2, att);
  agg_kernel<<<dim3(256, 2), 256, 0, stream>>>(att, wgt, agg);
  conv_kernel<<<512, 256, 0, stream>>>(xTp, agg, out);
}

// Round 15
// 108.134 us; speedup vs baseline: 1.3200x; 1.3200x over previous
//
#include <hip/hip_runtime.h>

typedef __attribute__((ext_vector_type(8))) short bf16x8;
typedef __attribute__((ext_vector_type(4))) float f32x4;

#define AS3 __attribute__((address_space(3)))
#define AS1 __attribute__((address_space(1)))

__device__ __forceinline__ unsigned short f2bf(float f) {
  unsigned u = __float_as_uint(f);
  u += 0x7fffu + ((u >> 16) & 1u);
  return (unsigned short)(u >> 16);
}
__device__ __forceinline__ float bf2f(unsigned short v) {
  return __uint_as_float((unsigned)v << 16);
}

// ---------------- kernel 1: transpose + pad + bf16 + border-zero + pool partials
__global__ void transpose_kernel(const float* __restrict__ x,
                                 unsigned short* __restrict__ xTp,
                                 float* __restrict__ part) {
  __shared__ unsigned short tb[64][258];
  __shared__ float redf[4][256];
  const int blk = blockIdx.x;
  const int b = blk >> 6, y = blk & 63;
  const int t = threadIdx.x;
  const int l = t & 63, w = t >> 6;
  const int coff = l >> 4;
  const int x4 = (l & 15) << 2;
  const float* src = x + (size_t)b * 256 * 4096 + (size_t)y * 64;
#pragma unroll 4
  for (int i = 0; i < 16; ++i) {
    const int c = w * 64 + i * 4 + coff;
    const float4 v = *reinterpret_cast<const float4*>(&src[(size_t)c * 4096 + x4]);
    tb[x4 + 0][c] = f2bf(v.x);
    tb[x4 + 1][c] = f2bf(v.y);
    tb[x4 + 2][c] = f2bf(v.z);
    tb[x4 + 3][c] = f2bf(v.w);
  }
  __syncthreads();
  unsigned short* dstb = xTp + (size_t)b * (4356 * 256);
  unsigned short* dst = dstb + ((size_t)(y + 1) * 66 + 1) * 256;
  float s0 = 0.f, s1 = 0.f, s2 = 0.f, s3 = 0.f;
#pragma unroll 4
  for (int i = 0; i < 16; ++i) {
    const int xx = w * 16 + i;
    ushort2 v0 = *(const ushort2*)&tb[xx][l * 4];
    ushort2 v1 = *(const ushort2*)&tb[xx][l * 4 + 2];
    s0 += bf2f(v0.x); s1 += bf2f(v0.y); s2 += bf2f(v1.x); s3 += bf2f(v1.y);
    ushort4 v = {v0.x, v0.y, v1.x, v1.y};
    *(ushort4*)&dst[(size_t)xx * 256 + l * 4] = v;
  }
  redf[w][l * 4 + 0] = s0;
  redf[w][l * 4 + 1] = s1;
  redf[w][l * 4 + 2] = s2;
  redf[w][l * 4 + 3] = s3;
  unsigned short* rowpad = dstb + ((size_t)(y + 1) * 66) * 256;
  rowpad[t] = 0;
  rowpad[65 * 256 + t] = 0;
  if (y == 0)
    for (int xx = 0; xx < 66; ++xx) dstb[(size_t)xx * 256 + t] = 0;
  if (y == 63)
    for (int xx = 0; xx < 66; ++xx) dstb[(size_t)(65 * 66 + xx) * 256 + t] = 0;
  __syncthreads();
  part[((size_t)(b * 64 + y)) * 256 + t] =
      redf[0][t] + redf[1][t] + redf[2][t] + redf[3][t];
}

// ---------------- kernel 1c: finish pool ----------
__global__ void poolfin_kernel(const float* __restrict__ part,
                               float* __restrict__ pooled) {
  const int b = blockIdx.x, c = threadIdx.x;
  float s = 0.f;
  for (int y = 0; y < 64; ++y) s += part[((size_t)(b * 64 + y)) * 256 + c];
  pooled[b * 256 + c] = s * (1.0f / 4096.0f);
}

// ---------------- kernel 2: attention MLP + softmax ----------------
__global__ void attn_kernel(const float* __restrict__ pooled,
                            const float* __restrict__ w1,
                            const float* __restrict__ bng,
                            const float* __restrict__ bnb,
                            const float* __restrict__ bnm,
                            const float* __restrict__ bnv,
                            const float* __restrict__ w2,
                            float* __restrict__ att) {
  __shared__ float hbuf[256];
  const int t = threadIdx.x;
  const int b = t >> 4, i = t & 15;
  float s = 0.f;
  for (int c = 0; c < 256; ++c) s += pooled[b * 256 + c] * w1[i * 256 + c];
  float h = (s - bnm[i]) * rsqrtf(bnv[i] + 1e-5f) * bng[i] + bnb[i];
  hbuf[t] = fmaxf(h, 0.f);
  __syncthreads();
  if (t < 64) {
    const int bb = t >> 2, k = t & 3;
    float l = 0.f;
    for (int j = 0; j < 16; ++j) l += hbuf[bb * 16 + j] * w2[k * 16 + j];
    float m = l;
    m = fmaxf(m, __shfl_xor(m, 1, 64));
    m = fmaxf(m, __shfl_xor(m, 2, 64));
    float e = expf(l - m);
    float sum = e;
    sum += __shfl_xor(sum, 1, 64);
    sum += __shfl_xor(sum, 2, 64);
    att[bb * 4 + k] = e / sum;
  }
}

// ---------------- kernel 3: aggregate per-sample kernels ----------------
__global__ void agg_kernel(const float* __restrict__ att,
                           const float* __restrict__ wgt,
                           unsigned short* __restrict__ agg) {
  const int o = blockIdx.x;
  const int bh = blockIdx.y;
  const int c = threadIdx.x;
  float w[4][9];
#pragma unroll
  for (int k = 0; k < 4; ++k) {
    const float* wp = wgt + ((size_t)((k << 8) + o) * 256 + c) * 9;
#pragma unroll
    for (int t = 0; t < 9; ++t) w[k][t] = wp[t];
  }
  __shared__ float attS[64];
  if (c < 64) attS[c] = att[c];
  __syncthreads();
#pragma unroll 1
  for (int b = bh * 8; b < bh * 8 + 8; ++b) {
    const float a0 = attS[b * 4 + 0], a1 = attS[b * 4 + 1];
    const float a2 = attS[b * 4 + 2], a3 = attS[b * 4 + 3];
#pragma unroll
    for (int t = 0; t < 9; ++t) {
      const float v = a0 * w[0][t] + a1 * w[1][t] + a2 * w[2][t] + a3 * w[3][t];
      agg[(((size_t)(b * 9 + t) * 256) + o) * 256 + c] = f2bf(v);
    }
  }
}

// ---------------- kernel 4: per-sample implicit-GEMM conv (bf16 MFMA) ----
// FROZEN at session-best structure (R13, 69.5us): tile 256x128, 4 waves
// (2Mx2N) of 128x64, A-halo staged per c0 (reused 9 taps), B ring-4
// stage-ahead-2, 1 barrier/tap, end-of-tap frag prefetch.
__global__ __launch_bounds__(256, 2) void conv_kernel(
    const unsigned short* __restrict__ xTp,
    const unsigned short* __restrict__ agg,
    float* __restrict__ out) {
  __shared__ unsigned short lds[448 * 32 + 4 * 128 * 32];  // 61440 B
  AS3 char* ldsA3 = (AS3 char*)lds;
  AS3 char* ldsB3 = ((AS3 char*)lds) + 28672;

  const int bid = blockIdx.x;
  const int b = bid & 15;   // XCD = b%8
  const int rest = bid >> 4;
  const int mt = rest >> 1;
  const int nh = rest & 1;
  const int p0 = mt << 8;
  const int rowA0 = mt * 264;

  const int tid = threadIdx.x;
  const int lane = tid & 63;
  const int wave = tid >> 6;
  const int wm = wave >> 1;
  const int wn = wave & 1;

  const int srow = tid >> 2;
  const int scol = ((tid & 3) ^ ((tid >> 3) & 3)) << 3;
  const int sdst = srow * 64 + (tid & 3) * 16;

  const unsigned short* xbs =
      xTp + (size_t)b * (4356 * 256) + (size_t)rowA0 * 256 + scol;
  const unsigned short* aggs =
      agg + ((size_t)(b * 9) * 256 + nh * 128 + srow) * 256 + scol;

  auto stageA = [&](int c0) {
#pragma unroll
    for (int i = 0; i < 7; ++i) {
      const int h = srow + (i << 6);
      const int hs = h > 395 ? 395 : h;
      __builtin_amdgcn_global_load_lds(
          (const AS1 void*)(xbs + (size_t)hs * 256 + c0 * 32),
          (AS3 void*)(ldsA3 + sdst + (i << 12)), 16, 0, 0);
    }
  };
  auto stageB = [&](int c02, int tap2, int slot) {
#pragma unroll
    for (int j = 0; j < 2; ++j) {
      __builtin_amdgcn_global_load_lds(
          (const AS1 void*)(aggs + tap2 * 65536 + (j << 14) + c02 * 32),
          (AS3 void*)(ldsB3 + slot * 8192 + sdst + (j << 12)), 16, 0, 0);
    }
  };

  const int l15 = lane & 15;
  const int lhi = lane >> 4;
  const int hb0 = wm * 132 + l15;
  const int rslotB = (lhi ^ ((l15 >> 1) & 3)) << 4;
  int boffs[4];
#pragma unroll
  for (int n = 0; n < 4; ++n)
    boffs[n] = 28672 + (wn * 64 + n * 16 + l15) * 64 + rslotB;

  f32x4 acc[8][4];
#pragma unroll
  for (int m = 0; m < 8; ++m)
#pragma unroll
    for (int n = 0; n < 4; ++n) acc[m][n] = (f32x4){0.f, 0.f, 0.f, 0.f};

#define LDFRAGS(tt)                                                        \
  {                                                                        \
    const int dy_ = (tt) / 3, dx_ = (tt) % 3;                              \
    const int slotR_ = (c0 + (tt)) & 3;                                    \
    _Pragma("unroll") for (int m = 0; m < 8; ++m) {                        \
      const int h_ = hb0 + ((m >> 2) + dy_) * 66 + (m & 3) * 16 + dx_;     \
      af[m] = *(const bf16x8*)((const char*)lds + h_ * 64 +                \
                               ((lhi ^ ((h_ >> 1) & 3)) << 4));            \
    }                                                                      \
    _Pragma("unroll") for (int n = 0; n < 4; ++n)                          \
      bfr[n] = *(const bf16x8*)((const char*)lds + slotR_ * 8192 + boffs[n]); \
  }

  stageB(0, 0, 0);
  stageB(0, 1, 1);

#pragma unroll 1
  for (int c0 = 0; c0 < 8; ++c0) {
    __builtin_amdgcn_s_barrier();  // all waves consumed A(c0-1)
    stageA(c0);
    asm volatile("s_waitcnt vmcnt(0)" ::: "memory");
    __builtin_amdgcn_s_barrier();
    __builtin_amdgcn_sched_barrier(0);
    bf16x8 af[8], bfr[4];
    LDFRAGS(0);  // preload tap0 frags (B slot c0&3 drained above)
#pragma unroll
    for (int tap = 0; tap < 9; ++tap) {
      if (tap != 0) {
        asm volatile("s_waitcnt vmcnt(0)" ::: "memory");
        __builtin_amdgcn_s_barrier();
        __builtin_amdgcn_sched_barrier(0);
      }
      {  // stage B(tap+2)
        int c02, tap2;
        if (tap <= 6) { c02 = c0; tap2 = tap + 2; }
        else { c02 = c0 + 1; tap2 = tap - 7; }
        if (c02 > 7) { c02 = 7; tap2 = 8; }  // tail dup, uniform counts
        stageB(c02, tap2, (c0 + tap + 2) & 3);
      }
      __builtin_amdgcn_s_setprio(1);
#pragma unroll
      for (int m = 0; m < 8; ++m)
#pragma unroll
        for (int n = 0; n < 4; ++n)
          acc[m][n] = __builtin_amdgcn_mfma_f32_16x16x32_bf16(af[m], bfr[n],
                                                              acc[m][n], 0, 0, 0);
      __builtin_amdgcn_s_setprio(0);
      if (tap < 8) LDFRAGS(tap + 1);
    }
  }

  // epilogue: D row=(lane>>4)*4+reg is p, col=lane&15 is cout
#pragma unroll
  for (int m = 0; m < 8; ++m) {
    const int p = p0 + wm * 128 + (m >> 2) * 64 + (m & 3) * 16 + (lhi << 2);
#pragma unroll
    for (int n = 0; n < 4; ++n) {
      const int co = nh * 128 + wn * 64 + n * 16 + l15;
      float* dst = out + ((size_t)(b * 256 + co) << 12) + p;
      *reinterpret_cast<f32x4*>(dst) = acc[m][n];
    }
  }
#undef LDFRAGS
}

extern "C" void kernel_launch(void* const* d_in, const int* in_sizes, int n_in,
                              void* d_out, int out_size, void* d_ws, size_t ws_size,
                              hipStream_t stream) {
  const float* x = (const float*)d_in[0];
  const float* w1 = (const float*)d_in[1];
  const float* bng = (const float*)d_in[2];
  const float* bnb = (const float*)d_in[3];
  const float* bnm = (const float*)d_in[4];
  const float* bnv = (const float*)d_in[5];
  const float* w2 = (const float*)d_in[6];
  const float* wgt = (const float*)d_in[7];
  float* out = (float*)d_out;

  char* ws = (char*)d_ws;
  const size_t xtp_bytes = (size_t)16 * 4356 * 256 * 2;    // 35,684,352
  const size_t agg_bytes = (size_t)16 * 9 * 256 * 256 * 2; // 18,874,368
  unsigned short* xTp = (unsigned short*)ws;
  unsigned short* agg = (unsigned short*)(ws + xtp_bytes);
  float* pooled = (float*)(ws + xtp_bytes + agg_bytes);
  float* att = (float*)(ws + xtp_bytes + agg_bytes + 16384);
  float* part = (float*)(ws + xtp_bytes + agg_bytes + 20480);

  transpose_kernel<<<1024, 256, 0, stream>>>(x, xTp, part);
  poolfin_kernel<<<16, 256, 0, stream>>>(part, pooled);
  attn_kernel<<<1, 256, 0, stream>>>(pooled, w1, bng, bnb, bnm, bnv, w2, att);
  agg_kernel<<<dim3(256, 2), 256, 0, stream>>>(att, wgt, agg);
  conv_kernel<<<512, 256, 0, stream>>>(xTp, agg, out);
}